// Round 1
// baseline (947.792 us; speedup 1.0000x reference)
//
#include <hip/hip_runtime.h>
#include <stdint.h>

// MoE FFN: router(fp64 logits) -> slot assign -> scatter x->bf16 -> W transpose/convert
// -> GEMM1(gelu) -> GEMM2(weight+scatter) -> combine.  m97-style MFMA GEMM:
// 128x128 tile, BK=32, mfma_f32_16x16x32_bf16, global_load_lds width=16.

#define NEXP 7
#define KTOP 2
#define CAP 3072
#define DM 1024
#define HF 4096
#define TT 8192

typedef __bf16 bf16x8 __attribute__((ext_vector_type(8)));
typedef float f32x4 __attribute__((ext_vector_type(4)));

__device__ __forceinline__ unsigned short f2bf(float v) {
  union { float f; unsigned u; } a; a.f = v;
  unsigned r = a.u + 0x7FFFu + ((a.u >> 16) & 1u);   // RNE
  return (unsigned short)(r >> 16);
}
__device__ __forceinline__ float bf2f(unsigned short h) {
  union { unsigned u; float f; } a; a.u = ((unsigned)h) << 16; return a.f;
}
__device__ __forceinline__ float gelu_t(float v) {
  // tanh-approx gelu (jax.nn.gelu approximate=True)
  float u = 0.7978845608028654f * (v + 0.044715f * v * v * v);
  float ex = __expf(2.0f * u);
  float th = 1.0f - 2.0f / (ex + 1.0f);
  return 0.5f * v * (1.0f + th);
}
__device__ __forceinline__ void gl2lds16(const void* g, void* l) {
  __builtin_amdgcn_global_load_lds(
      (const __attribute__((address_space(1))) unsigned int*)g,
      (__attribute__((address_space(3))) unsigned int*)l, 16, 0, 0);
}

__global__ void init_counts(int* counts) {
  if (threadIdx.x < NEXP) counts[threadIdx.x] = 0;
}

// one wave per token; fp64 logits so top-2 matches the np reference exactly
__global__ void router_kernel(const float* __restrict__ x, const float* __restrict__ Wg,
                              int* __restrict__ counts, int* __restrict__ flatE,
                              int* __restrict__ flatSlot, int* __restrict__ tokOfSlot,
                              float* __restrict__ wOfSlot) {
  int wave = threadIdx.x >> 6, lane = threadIdx.x & 63;
  int t = blockIdx.x * 4 + wave;
  double acc[NEXP];
#pragma unroll
  for (int e = 0; e < NEXP; ++e) acc[e] = 0.0;
  const float* xr = x + (long)t * DM;
  for (int j = 0; j < DM / 64; ++j) {
    int d = j * 64 + lane;
    double xv = (double)xr[d];
#pragma unroll
    for (int e = 0; e < NEXP; ++e) acc[e] += xv * (double)Wg[d * NEXP + e];
  }
#pragma unroll
  for (int e = 0; e < NEXP; ++e) {
#pragma unroll
    for (int off = 32; off > 0; off >>= 1) acc[e] += __shfl_down(acc[e], off);
  }
  if (lane == 0) {
    int i1 = 0; double l1 = acc[0];
    for (int e2 = 1; e2 < NEXP; ++e2) if (acc[e2] > l1) { l1 = acc[e2]; i1 = e2; }
    int i2 = -1; double l2 = -1e300;
    for (int e2 = 0; e2 < NEXP; ++e2) if (e2 != i1 && acc[e2] > l2) { l2 = acc[e2]; i2 = e2; }
    float w1 = (float)(1.0 / (1.0 + exp(l2 - l1)));  // softmax top-2 renormalized
    float w2 = 1.0f - w1;
    int fi0 = t * 2, fi1 = t * 2 + 1;
    int p0 = atomicAdd(&counts[i1], 1);
    flatE[fi0] = i1; flatSlot[fi0] = (p0 < CAP) ? p0 : CAP;
    if (p0 < CAP) { tokOfSlot[i1 * CAP + p0] = fi0; wOfSlot[i1 * CAP + p0] = w1; }
    int p1 = atomicAdd(&counts[i2], 1);
    flatE[fi1] = i2; flatSlot[fi1] = (p1 < CAP) ? p1 : CAP;
    if (p1 < CAP) { tokOfSlot[i2 * CAP + p1] = fi1; wOfSlot[i2 * CAP + p1] = w2; }
  }
}

// [R][C] fp32 -> [C][R] bf16, 64x64 LDS tile (pad 65 => conflict-free)
__global__ void transcvt(const float* __restrict__ in, unsigned short* __restrict__ out,
                         int R, int C) {
  __shared__ float tile[64][65];
  long base = (long)blockIdx.z * (long)R * (long)C;
  const float* inp = in + base;
  unsigned short* outp = out + base;
  int c0 = blockIdx.x * 64, r0 = blockIdx.y * 64;
  int lx = threadIdx.x & 63, ly = threadIdx.x >> 6;
#pragma unroll
  for (int i = 0; i < 16; ++i) {
    int r = ly + i * 4;
    tile[r][lx] = inp[(long)(r0 + r) * C + c0 + lx];
  }
  __syncthreads();
#pragma unroll
  for (int i = 0; i < 16; ++i) {
    int c = ly + i * 4;
    outp[(long)(c0 + c) * R + r0 + lx] = f2bf(tile[lx][c]);
  }
}

__global__ void scatter_x(const float* __restrict__ x, const int* __restrict__ flatE,
                          const int* __restrict__ flatSlot, unsigned short* __restrict__ xb) {
  int fi = blockIdx.x;
  int s = flatSlot[fi];
  if (s >= CAP) return;
  int e = flatE[fi];
  const float4* xr = (const float4*)(x + (long)(fi >> 1) * DM);
  float4 v = xr[threadIdx.x];
  ushort4 o; o.x = f2bf(v.x); o.y = f2bf(v.y); o.z = f2bf(v.z); o.w = f2bf(v.w);
  ((ushort4*)(xb + ((long)e * CAP + s) * DM))[threadIdx.x] = o;
}

// C = A[M,K] @ Bt[N,K]^T per expert; EPI=0: gelu->bf16 to Ce; EPI=1: w*val->bf16 scatter to yflat
template <int EPI>
__global__ __launch_bounds__(256, 2) void gemm_bt(
    const unsigned short* __restrict__ A, const unsigned short* __restrict__ Bt,
    void* __restrict__ Cout, const int* __restrict__ counts,
    const int* __restrict__ tokOfSlot, const float* __restrict__ wOfSlot,
    int K, int N, int eoff, long aexps, long cexps) {
  __shared__ unsigned short sA[128 * 32];
  __shared__ unsigned short sB[128 * 32];
  int e = eoff + blockIdx.z;
  int mcnt = counts[e]; mcnt = mcnt < CAP ? mcnt : CAP;
  int m0 = blockIdx.y * 128;
  if (m0 >= mcnt) return;          // skip empty capacity tiles
  int n0 = blockIdx.x * 128;
  const unsigned short* Ae = A + (long)blockIdx.z * aexps;
  const unsigned short* Be = Bt + (long)e * (long)N * (long)K;

  int tid = threadIdx.x;
  int lane = tid & 63, wave = tid >> 6;
  int lm = lane & 15, quad = lane >> 4;
  int wm = (wave & 1) * 64, wn = (wave >> 1) * 64;

  int ra = tid >> 2;            // staging row 0..63
  int ca = (tid & 3) * 8;       // staging col chunk
  const unsigned short* Ab0 = Ae + (long)(m0 + ra) * K + ca;
  const unsigned short* Ab1 = Ae + (long)(m0 + 64 + ra) * K + ca;
  const unsigned short* Bb0 = Be + (long)(n0 + ra) * K + ca;
  const unsigned short* Bb1 = Be + (long)(n0 + 64 + ra) * K + ca;
  unsigned short* sAp0 = &sA[tid * 8];
  unsigned short* sAp1 = &sA[(tid + 256) * 8];
  unsigned short* sBp0 = &sB[tid * 8];
  unsigned short* sBp1 = &sB[(tid + 256) * 8];

  f32x4 acc[4][4];
#pragma unroll
  for (int i = 0; i < 4; ++i)
#pragma unroll
    for (int j = 0; j < 4; ++j) acc[i][j] = f32x4{0.f, 0.f, 0.f, 0.f};

  for (int k0 = 0; k0 < K; k0 += 32) {
    gl2lds16(Ab0 + k0, sAp0);
    gl2lds16(Ab1 + k0, sAp1);
    gl2lds16(Bb0 + k0, sBp0);
    gl2lds16(Bb1 + k0, sBp1);
    __syncthreads();
    bf16x8 aF[4], bF[4];
#pragma unroll
    for (int mi = 0; mi < 4; ++mi)
      aF[mi] = *(const bf16x8*)&sA[(wm + mi * 16 + lm) * 32 + quad * 8];
#pragma unroll
    for (int ni = 0; ni < 4; ++ni)
      bF[ni] = *(const bf16x8*)&sB[(wn + ni * 16 + lm) * 32 + quad * 8];
#pragma unroll
    for (int mi = 0; mi < 4; ++mi)
#pragma unroll
      for (int ni = 0; ni < 4; ++ni)
        acc[mi][ni] = __builtin_amdgcn_mfma_f32_16x16x32_bf16(aF[mi], bF[ni], acc[mi][ni], 0, 0, 0);
    __syncthreads();
  }

  // C/D layout: col = lane&15 (N), row = quad*4 + r (M)  [m89-verified]
  if (EPI == 0) {
    unsigned short* Ce = (unsigned short*)Cout + (long)blockIdx.z * cexps;
#pragma unroll
    for (int mi = 0; mi < 4; ++mi) {
      int mb = m0 + wm + mi * 16 + quad * 4;
#pragma unroll
      for (int r = 0; r < 4; ++r) {
        int m = mb + r;
        if (m < mcnt) {
#pragma unroll
          for (int ni = 0; ni < 4; ++ni) {
            int n = n0 + wn + ni * 16 + lm;
            Ce[(long)m * N + n] = f2bf(gelu_t(acc[mi][ni][r]));
          }
        }
      }
    }
  } else {
    unsigned short* Y = (unsigned short*)Cout;
#pragma unroll
    for (int mi = 0; mi < 4; ++mi) {
      int mb = m0 + wm + mi * 16 + quad * 4;
#pragma unroll
      for (int r = 0; r < 4; ++r) {
        int m = mb + r;
        if (m < mcnt) {
          int fi = tokOfSlot[e * CAP + m];
          float w = wOfSlot[e * CAP + m];
#pragma unroll
          for (int ni = 0; ni < 4; ++ni) {
            int n = n0 + wn + ni * 16 + lm;
            Y[(long)fi * N + n] = f2bf(w * acc[mi][ni][r]);
          }
        }
      }
    }
  }
}

__global__ void combine_k(const unsigned short* __restrict__ yflat,
                          const int* __restrict__ flatSlot, float* __restrict__ out) {
  int t = blockIdx.x;
  bool k0 = flatSlot[2 * t] < CAP, k1 = flatSlot[2 * t + 1] < CAP;
  const ushort4* y0 = (const ushort4*)(yflat + (long)(2 * t) * DM);
  const ushort4* y1 = (const ushort4*)(yflat + (long)(2 * t + 1) * DM);
  ushort4 a = y0[threadIdx.x], b = y1[threadIdx.x];
  float4 r;
  r.x = (k0 ? bf2f(a.x) : 0.f) + (k1 ? bf2f(b.x) : 0.f);
  r.y = (k0 ? bf2f(a.y) : 0.f) + (k1 ? bf2f(b.y) : 0.f);
  r.z = (k0 ? bf2f(a.z) : 0.f) + (k1 ? bf2f(b.z) : 0.f);
  r.w = (k0 ? bf2f(a.w) : 0.f) + (k1 ? bf2f(b.w) : 0.f);
  ((float4*)(out + (long)t * DM))[threadIdx.x] = r;
}

extern "C" void kernel_launch(void* const* d_in, const int* in_sizes, int n_in,
                              void* d_out, int out_size, void* d_ws, size_t ws_size,
                              hipStream_t stream) {
  const float* x  = (const float*)d_in[0];
  const float* Wg = (const float*)d_in[1];
  const float* W1 = (const float*)d_in[2];
  const float* W2 = (const float*)d_in[3];
  float* out = (float*)d_out;

  char* ws = (char*)d_ws;
  size_t off = 0;
  auto alloc = [&](size_t b) { void* p = ws + off; off = (off + b + 255) & ~(size_t)255; return p; };
  int* counts            = (int*)alloc(NEXP * 4);
  int* flatE             = (int*)alloc((size_t)TT * KTOP * 4);
  int* flatSlot          = (int*)alloc((size_t)TT * KTOP * 4);
  int* tokOfSlot         = (int*)alloc((size_t)NEXP * CAP * 4);
  float* wOfSlot         = (float*)alloc((size_t)NEXP * CAP * 4);
  unsigned short* Wb1    = (unsigned short*)alloc((size_t)NEXP * DM * HF * 2);  // [E][H][D]
  unsigned short* Wb2    = (unsigned short*)alloc((size_t)NEXP * DM * HF * 2);  // [E][D][H]
  unsigned short* xb     = (unsigned short*)alloc((size_t)NEXP * CAP * DM * 2); // [E][CAP][D]
  unsigned short* yflat  = (unsigned short*)alloc((size_t)TT * KTOP * DM * 2);  // [T*K][D]
  size_t hbA = (size_t)NEXP * CAP * HF * 2;   // [E][CAP][H]
  size_t hbB = (size_t)CAP * HF * 2;          // shared per-expert
  int planA = (off + hbA) <= ws_size;
  unsigned short* hb = (unsigned short*)alloc(planA ? hbA : hbB);

  init_counts<<<1, 64, 0, stream>>>(counts);
  router_kernel<<<TT / 4, 256, 0, stream>>>(x, Wg, counts, flatE, flatSlot, tokOfSlot, wOfSlot);
  transcvt<<<dim3(HF / 64, DM / 64, NEXP), 256, 0, stream>>>(W1, Wb1, DM, HF);
  transcvt<<<dim3(DM / 64, HF / 64, NEXP), 256, 0, stream>>>(W2, Wb2, HF, DM);
  scatter_x<<<TT * KTOP, 256, 0, stream>>>(x, flatE, flatSlot, xb);

  if (planA) {
    gemm_bt<0><<<dim3(HF / 128, CAP / 128, NEXP), 256, 0, stream>>>(
        xb, Wb1, hb, counts, tokOfSlot, wOfSlot, DM, HF, 0, (long)CAP * DM, (long)CAP * HF);
    gemm_bt<1><<<dim3(DM / 128, CAP / 128, NEXP), 256, 0, stream>>>(
        hb, Wb2, yflat, counts, tokOfSlot, wOfSlot, HF, DM, 0, (long)CAP * HF, 0);
  } else {
    for (int e = 0; e < NEXP; ++e) {
      gemm_bt<0><<<dim3(HF / 128, CAP / 128, 1), 256, 0, stream>>>(
          xb + (size_t)e * CAP * DM, Wb1, hb, counts, tokOfSlot, wOfSlot, DM, HF, e, 0, 0);
      gemm_bt<1><<<dim3(DM / 128, CAP / 128, 1), 256, 0, stream>>>(
          hb, Wb2, yflat, counts, tokOfSlot, wOfSlot, HF, DM, e, 0, 0);
    }
  }
  combine_k<<<TT, 256, 0, stream>>>(yflat, flatSlot, out);
}